// Round 1
// baseline (709.232 us; speedup 1.0000x reference)
//
#include <hip/hip_runtime.h>
#include <math.h>

// Problem constants (fixed by reference): B=64, N=512, D=64, H=4, C=64, L=3
// Workspace layout (floats): xbuf[2097152] | hbuf[8388608]  (yH aliases hbuf)

// ---------------------------------------------------------------------------
// Kernel A: h[gn][o] = sum_d x[gn][d] * W[o][d]   (gn over B*N, o over 256)
// Tile: 128 n x 128 o per block. LDS XOR-swizzled to kill bank conflicts.
// ---------------------------------------------------------------------------
__global__ __launch_bounds__(256) void lin_kernel(const float* __restrict__ x,
                                                  const float* __restrict__ W,
                                                  float* __restrict__ h) {
    __shared__ float Ws[128 * 64];
    __shared__ float Xs[128 * 64];
    const int tid = threadIdx.x;
    const int nblk = blockIdx.x >> 1;
    const int o0 = (blockIdx.x & 1) * 128;
    const int gn0 = nblk * 128;

    // Load W tile [o0, o0+128) x 64, swizzle col4' = d4 ^ ((row>>3)&7)
#pragma unroll
    for (int q = 0; q < 8; ++q) {
        int flat = q * 256 + tid;
        int row = flat >> 4, d4 = flat & 15;
        float4 v = *(const float4*)(W + (size_t)(o0 + row) * 64 + d4 * 4);
        *(float4*)(Ws + row * 64 + ((d4 ^ ((row >> 3) & 7)) << 2)) = v;
    }
    // Load x tile [gn0, gn0+128) x 64, swizzle col4' = d4 ^ (row&7)
#pragma unroll
    for (int q = 0; q < 8; ++q) {
        int flat = q * 256 + tid;
        int row = flat >> 4, d4 = flat & 15;
        float4 v = *(const float4*)(x + (size_t)(gn0 + row) * 64 + d4 * 4);
        *(float4*)(Xs + row * 64 + ((d4 ^ (row & 7)) << 2)) = v;
    }
    __syncthreads();

    const int og = tid >> 4;   // 0..15 -> o rows og*8+k
    const int ng = tid & 15;   // 0..15 -> n rows ng+16*j
    const int wsw = og & 7;
    const int xsw = ng & 7;
    float acc[8][8];
#pragma unroll
    for (int k = 0; k < 8; ++k)
#pragma unroll
        for (int j = 0; j < 8; ++j) acc[k][j] = 0.f;

#pragma unroll
    for (int d4 = 0; d4 < 16; ++d4) {
        float4 w4[8], x4[8];
#pragma unroll
        for (int k = 0; k < 8; ++k)
            w4[k] = *(const float4*)(Ws + (og * 8 + k) * 64 + ((d4 ^ wsw) << 2));
#pragma unroll
        for (int j = 0; j < 8; ++j)
            x4[j] = *(const float4*)(Xs + (ng + 16 * j) * 64 + ((d4 ^ xsw) << 2));
#pragma unroll
        for (int k = 0; k < 8; ++k)
#pragma unroll
            for (int j = 0; j < 8; ++j)
                acc[k][j] += w4[k].x * x4[j].x + w4[k].y * x4[j].y +
                             w4[k].z * x4[j].z + w4[k].w * x4[j].w;
    }

    // Store: thread owns o = o0 + og*8 + k (k contiguous -> float4 x2 per row)
#pragma unroll
    for (int j = 0; j < 8; ++j) {
        int gn = gn0 + ng + 16 * j;
        float* dst = h + (size_t)gn * 256 + o0 + og * 8;
        *(float4*)(dst) = make_float4(acc[0][j], acc[1][j], acc[2][j], acc[3][j]);
        *(float4*)(dst + 4) = make_float4(acc[4][j], acc[5][j], acc[6][j], acc[7][j]);
    }
}

// ---------------------------------------------------------------------------
// Kernel B: attention + aggregation for one (b, head). Sorted prefix-sum
// decomposition of softmax(leakyrelu(d_i + s_j)) -> O(N log N + N*C).
// yH may alias h (same [bn][head][c] indexing; column-phased, barrier-safe).
// ---------------------------------------------------------------------------
__global__ __launch_bounds__(256) void attn_kernel(const float* __restrict__ h,
                                                   const float* __restrict__ att_src,
                                                   const float* __restrict__ att_dst,
                                                   float* __restrict__ yH) {
    const int b = blockIdx.x >> 2;
    const int head = blockIdx.x & 3;
    const int t = threadIdx.x;

    __shared__ float att_s[64], att_d[64];
    __shared__ float s_val[512];
    __shared__ int   s_idx[512];
    __shared__ float dArr[512];
    __shared__ float E1[512], E2[512];
    __shared__ float z1suf[513], z2pre[513];
    __shared__ float aZv[512], bZv[512];
    __shared__ int   kArr[512];
    __shared__ float A1[512 * 9], A2[512 * 9];
    __shared__ float segs1[32 * 8], segs2[32 * 8];
    __shared__ float tot2[8];

    if (t < 64) att_s[t] = att_src[head * 64 + t];
    else if (t < 128) att_d[t - 64] = att_dst[head * 64 + (t - 64)];
    __syncthreads();

    // s_j = h[j] . att_src ; d_i = h[i] . att_dst
    for (int rr = 0; rr < 2; ++rr) {
        int j = t + rr * 256;
        const float* hrow = h + ((size_t)(b * 512 + j) * 4 + head) * 64;
        float as = 0.f, ad = 0.f;
#pragma unroll
        for (int d4 = 0; d4 < 16; ++d4) {
            float4 hv = *(const float4*)(hrow + d4 * 4);
            float4 sv = *(const float4*)(att_s + d4 * 4);
            float4 dv = *(const float4*)(att_d + d4 * 4);
            as += hv.x * sv.x + hv.y * sv.y + hv.z * sv.z + hv.w * sv.w;
            ad += hv.x * dv.x + hv.y * dv.y + hv.z * dv.z + hv.w * dv.w;
        }
        s_val[j] = as; s_idx[j] = j; dArr[j] = ad;
    }
    __syncthreads();

    // Bitonic sort ascending (value + original index)
    for (int k = 2; k <= 512; k <<= 1) {
        for (int j = k >> 1; j > 0; j >>= 1) {
            for (int rr = 0; rr < 2; ++rr) {
                int i = t + rr * 256;
                int l = i ^ j;
                if (l > i) {
                    float a = s_val[i], c = s_val[l];
                    bool up = ((i & k) == 0);
                    if (up ? (a > c) : (a < c)) {
                        s_val[i] = c; s_val[l] = a;
                        int ia = s_idx[i]; s_idx[i] = s_idx[l]; s_idx[l] = ia;
                    }
                }
            }
            __syncthreads();
        }
    }

    const float M = s_val[511];
    for (int rr = 0; rr < 2; ++rr) {
        int r = t + rr * 256;
        float sv = s_val[r] - M;
        E1[r] = __expf(sv);
        E2[r] = __expf(0.2f * sv);
    }
    __syncthreads();

    // Scalar scans: z1suf[r] = sum_{r'>=r} E1 (z1suf[512]=0);
    //               z2pre[r] = sum_{r'<r} E2 (z2pre[512]=total)
    if (t < 64) {
        float p1 = 0.f, p2 = 0.f;
#pragma unroll
        for (int q = 0; q < 8; ++q) { p1 += E1[t * 8 + q]; p2 += E2[t * 8 + q]; }
        segs1[t] = p1; segs2[t] = p2;
    }
    __syncthreads();
    if (t < 64) {
        float suf = 0.f, pre = 0.f;
        for (int s = t + 1; s < 64; ++s) suf += segs1[s];
        for (int s = 0; s < t; ++s) pre += segs2[s];
        float run = suf;
        for (int q = 7; q >= 0; --q) { run += E1[t * 8 + q]; z1suf[t * 8 + q] = run; }
        float run2 = pre;
        for (int q = 0; q < 8; ++q) { z2pre[t * 8 + q] = run2; run2 += E2[t * 8 + q]; }
        if (t == 63) z2pre[512] = run2;
        if (t == 0) z1suf[512] = 0.f;
    }
    __syncthreads();

    // Per-i: crossover k_i, branch scales, normalizer
    for (int rr = 0; rr < 2; ++rr) {
        int i = t + rr * 256;
        float d = dArr[i];
        int lo = 0, hi = 512;
        while (lo < hi) {
            int mid = (lo + hi) >> 1;
            if (d + s_val[mid] >= 0.f) hi = mid; else lo = mid + 1;
        }
        int k = lo;
        float g = d + M;
        float G = (g >= 0.f) ? g : 0.2f * g;   // keeps denominator >= 1
        float al = __expf(g - G);
        float be = __expf(0.2f * g - G);
        float Z = al * z1suf[k] + be * z2pre[k];
        float inv = 1.0f / Z;
        aZv[i] = al * inv; bZv[i] = be * inv; kArr[i] = k;
    }
    __syncthreads();

    // Channel chunks of 8: weighted suffix (E1*h) + exclusive prefix (E2*h)
    for (int cc = 0; cc < 8; ++cc) {
        for (int rr = 0; rr < 2; ++rr) {
            int r = t + rr * 256;
            int jsrc = s_idx[r];
            const float* hp = h + ((size_t)(b * 512 + jsrc) * 4 + head) * 64 + cc * 8;
            float4 h0 = *(const float4*)(hp);
            float4 h1 = *(const float4*)(hp + 4);
            float e1 = E1[r], e2 = E2[r];
            float hv[8] = {h0.x, h0.y, h0.z, h0.w, h1.x, h1.y, h1.z, h1.w};
#pragma unroll
            for (int c = 0; c < 8; ++c) {
                A1[r * 9 + c] = e1 * hv[c];
                A2[r * 9 + c] = e2 * hv[c];
            }
        }
        __syncthreads();
        {
            int cl = t & 7, seg = t >> 3;
            int r0 = seg * 16;
            float s1 = 0.f, s2 = 0.f;
#pragma unroll
            for (int q = 0; q < 16; ++q) { s1 += A1[(r0 + q) * 9 + cl]; s2 += A2[(r0 + q) * 9 + cl]; }
            segs1[seg * 8 + cl] = s1; segs2[seg * 8 + cl] = s2;
            __syncthreads();
            float suf = 0.f, pre = 0.f;
            for (int s = seg + 1; s < 32; ++s) suf += segs1[s * 8 + cl];
            for (int s = 0; s < seg; ++s) pre += segs2[s * 8 + cl];
            float run = suf;
            for (int q = 15; q >= 0; --q) {
                int r = r0 + q;
                float v = A1[r * 9 + cl];
                run += v;
                A1[r * 9 + cl] = run;            // inclusive suffix
            }
            float run2 = pre;
#pragma unroll
            for (int q = 0; q < 16; ++q) {
                int r = r0 + q;
                float v = A2[r * 9 + cl];
                A2[r * 9 + cl] = run2;           // exclusive prefix
                run2 += v;
            }
            if (seg == 31) tot2[cl] = run2;
        }
        __syncthreads();
        {
            int cl = t & 7;
            int ibase = t >> 3;
#pragma unroll
            for (int p = 0; p < 16; ++p) {
                int i = p * 32 + ibase;
                int k = kArr[i];
                float S1 = (k < 512) ? A1[k * 9 + cl] : 0.f;
                float P2 = (k < 512) ? A2[k * 9 + cl] : tot2[cl];
                float val = aZv[i] * S1 + bZv[i] * P2;
                yH[((size_t)(b * 512 + i) * 4 + head) * 64 + cc * 8 + cl] = val;
            }
        }
        __syncthreads();
    }
}

// ---------------------------------------------------------------------------
// Kernel C: x[bn][c] = relu( mean_h yH[bn][h][c] + bias[c] )
// ---------------------------------------------------------------------------
__global__ __launch_bounds__(256) void finalize_kernel(const float* __restrict__ yH,
                                                       const float* __restrict__ bias,
                                                       float* __restrict__ x) {
    int idx = blockIdx.x * 256 + threadIdx.x;   // over B*N*16 float4 groups
    int bn = idx >> 4, c4 = idx & 15;
    const float* yp = yH + (size_t)bn * 256 + c4 * 4;
    float4 v0 = *(const float4*)(yp);
    float4 v1 = *(const float4*)(yp + 64);
    float4 v2 = *(const float4*)(yp + 128);
    float4 v3 = *(const float4*)(yp + 192);
    float4 bs = *(const float4*)(bias + c4 * 4);
    float4 o;
    o.x = fmaxf(0.25f * (v0.x + v1.x + v2.x + v3.x) + bs.x, 0.f);
    o.y = fmaxf(0.25f * (v0.y + v1.y + v2.y + v3.y) + bs.y, 0.f);
    o.z = fmaxf(0.25f * (v0.z + v1.z + v2.z + v3.z) + bs.z, 0.f);
    o.w = fmaxf(0.25f * (v0.w + v1.w + v2.w + v3.w) + bs.w, 0.f);
    *(float4*)(x + (size_t)bn * 64 + c4 * 4) = o;
}

// ---------------------------------------------------------------------------
// Kernel D: out[b][d] = (mean_n x[b][n][:]) . readout_w[d][:] + readout_b[d]
// ---------------------------------------------------------------------------
__global__ __launch_bounds__(256) void readout_kernel(const float* __restrict__ x,
                                                      const float* __restrict__ rw,
                                                      const float* __restrict__ rb,
                                                      float* __restrict__ out) {
    __shared__ float red[4][64];
    __shared__ float pooled[64];
    int b = blockIdx.x, t = threadIdx.x;
    int c = t & 63, q = t >> 6;
    float acc = 0.f;
    for (int n = q; n < 512; n += 4) acc += x[((size_t)b * 512 + n) * 64 + c];
    red[q][c] = acc;
    __syncthreads();
    if (t < 64) pooled[t] = (red[0][t] + red[1][t] + red[2][t] + red[3][t]) * (1.0f / 512.0f);
    __syncthreads();
    if (t < 64) {
        float a = rb[t];
        for (int cc = 0; cc < 64; ++cc) a += pooled[cc] * rw[t * 64 + cc];
        out[b * 64 + t] = a;
    }
}

extern "C" void kernel_launch(void* const* d_in, const int* in_sizes, int n_in,
                              void* d_out, int out_size, void* d_ws, size_t ws_size,
                              hipStream_t stream) {
    const float* emb       = (const float*)d_in[0];
    const float* lin_w     = (const float*)d_in[1];
    const float* att_src   = (const float*)d_in[2];
    const float* att_dst   = (const float*)d_in[3];
    const float* conv_b    = (const float*)d_in[4];
    const float* readout_w = (const float*)d_in[5];
    const float* readout_b = (const float*)d_in[6];
    float* out = (float*)d_out;

    float* ws   = (float*)d_ws;
    float* xbuf = ws;                 // 2,097,152 floats
    float* hbuf = ws + 2097152;       // 8,388,608 floats (yH aliases hbuf; safe:
                                      // per-(b,head) slices, column-phased writes)

    for (int l = 0; l < 3; ++l) {
        const float* xin = (l == 0) ? emb : xbuf;
        lin_kernel<<<512, 256, 0, stream>>>(xin, lin_w + (size_t)l * 16384, hbuf);
        attn_kernel<<<256, 256, 0, stream>>>(hbuf, att_src + l * 256, att_dst + l * 256, hbuf);
        finalize_kernel<<<2048, 256, 0, stream>>>(hbuf, conv_b + l * 64, xbuf);
    }
    readout_kernel<<<64, 256, 0, stream>>>(xbuf, readout_w, readout_b, out);
}

// Round 2
// 374.653 us; speedup vs baseline: 1.8930x; 1.8930x over previous
//
#include <hip/hip_runtime.h>
#include <math.h>

// Problem constants (fixed by reference): B=64, N=512, D=64, H=4, C=64, L=3
// Workspace layout (floats): xbuf[2097152] | hbuf[8388608]  (yH aliases hbuf)

// ---------------------------------------------------------------------------
// Kernel A: h[gn][o] = sum_d x[gn][d] * W[o][d]   (gn over B*N, o over 256)
// Tile: 128 n x 128 o per block. LDS XOR-swizzled.
// R1 fix: d4 loop NOT unrolled + W streamed one float4 at a time -> keeps
// live VGPRs ~110 (R0 version spilled at 256 VGPRs: WRITE_SIZE was 9.5x h).
// ---------------------------------------------------------------------------
__global__ __launch_bounds__(256) void lin_kernel(const float* __restrict__ x,
                                                  const float* __restrict__ W,
                                                  float* __restrict__ h) {
    __shared__ float Ws[128 * 64];
    __shared__ float Xs[128 * 64];
    const int tid = threadIdx.x;
    const int nblk = blockIdx.x >> 1;
    const int o0 = (blockIdx.x & 1) * 128;
    const int gn0 = nblk * 128;

    // Load W tile [o0, o0+128) x 64, swizzle col4' = d4 ^ ((row>>3)&7)
#pragma unroll
    for (int q = 0; q < 8; ++q) {
        int flat = q * 256 + tid;
        int row = flat >> 4, d4 = flat & 15;
        float4 v = *(const float4*)(W + (size_t)(o0 + row) * 64 + d4 * 4);
        *(float4*)(Ws + row * 64 + ((d4 ^ ((row >> 3) & 7)) << 2)) = v;
    }
    // Load x tile [gn0, gn0+128) x 64, swizzle col4' = d4 ^ (row&7)
#pragma unroll
    for (int q = 0; q < 8; ++q) {
        int flat = q * 256 + tid;
        int row = flat >> 4, d4 = flat & 15;
        float4 v = *(const float4*)(x + (size_t)(gn0 + row) * 64 + d4 * 4);
        *(float4*)(Xs + row * 64 + ((d4 ^ (row & 7)) << 2)) = v;
    }
    __syncthreads();

    const int og = tid >> 4;   // 0..15 -> o cols og*8+k
    const int ng = tid & 15;   // 0..15 -> n rows ng+16*j
    const int wsw = og & 7;
    const int xsw = ng & 7;
    float acc[8][8];           // [k][j]
#pragma unroll
    for (int k = 0; k < 8; ++k)
#pragma unroll
        for (int j = 0; j < 8; ++j) acc[k][j] = 0.f;

#pragma unroll 1
    for (int d4 = 0; d4 < 16; ++d4) {
        float4 x4[8];
#pragma unroll
        for (int j = 0; j < 8; ++j)
            x4[j] = *(const float4*)(Xs + (ng + 16 * j) * 64 + ((d4 ^ xsw) << 2));
#pragma unroll
        for (int k = 0; k < 8; ++k) {
            float4 w = *(const float4*)(Ws + (og * 8 + k) * 64 + ((d4 ^ wsw) << 2));
#pragma unroll
            for (int j = 0; j < 8; ++j)
                acc[k][j] += w.x * x4[j].x + w.y * x4[j].y +
                             w.z * x4[j].z + w.w * x4[j].w;
        }
    }

    // Store: thread owns o = o0 + og*8 + k (k contiguous -> float4 x2 per row)
#pragma unroll
    for (int j = 0; j < 8; ++j) {
        int gn = gn0 + ng + 16 * j;
        float* dst = h + (size_t)gn * 256 + o0 + og * 8;
        *(float4*)(dst) = make_float4(acc[0][j], acc[1][j], acc[2][j], acc[3][j]);
        *(float4*)(dst + 4) = make_float4(acc[4][j], acc[5][j], acc[6][j], acc[7][j]);
    }
}

// ---------------------------------------------------------------------------
// Kernel B: attention + aggregation for one (b, head). Sorted prefix-sum
// decomposition of softmax(leakyrelu(d_i + s_j)) -> O(N log N + N*C).
// yH may alias h (same [bn][head][c] indexing; column-phased, barrier-safe).
// ---------------------------------------------------------------------------
__global__ __launch_bounds__(256) void attn_kernel(const float* __restrict__ h,
                                                   const float* __restrict__ att_src,
                                                   const float* __restrict__ att_dst,
                                                   float* __restrict__ yH) {
    const int b = blockIdx.x >> 2;
    const int head = blockIdx.x & 3;
    const int t = threadIdx.x;

    __shared__ float att_s[64], att_d[64];
    __shared__ float s_val[512];
    __shared__ int   s_idx[512];
    __shared__ float dArr[512];
    __shared__ float E1[512], E2[512];
    __shared__ float z1suf[513], z2pre[513];
    __shared__ float aZv[512], bZv[512];
    __shared__ int   kArr[512];
    __shared__ float A1[512 * 9], A2[512 * 9];
    __shared__ float segs1[32 * 8], segs2[32 * 8];
    __shared__ float tot2[8];

    if (t < 64) att_s[t] = att_src[head * 64 + t];
    else if (t < 128) att_d[t - 64] = att_dst[head * 64 + (t - 64)];
    __syncthreads();

    // s_j = h[j] . att_src ; d_i = h[i] . att_dst
    for (int rr = 0; rr < 2; ++rr) {
        int j = t + rr * 256;
        const float* hrow = h + ((size_t)(b * 512 + j) * 4 + head) * 64;
        float as = 0.f, ad = 0.f;
#pragma unroll
        for (int d4 = 0; d4 < 16; ++d4) {
            float4 hv = *(const float4*)(hrow + d4 * 4);
            float4 sv = *(const float4*)(att_s + d4 * 4);
            float4 dv = *(const float4*)(att_d + d4 * 4);
            as += hv.x * sv.x + hv.y * sv.y + hv.z * sv.z + hv.w * sv.w;
            ad += hv.x * dv.x + hv.y * dv.y + hv.z * dv.z + hv.w * dv.w;
        }
        s_val[j] = as; s_idx[j] = j; dArr[j] = ad;
    }
    __syncthreads();

    // Bitonic sort ascending (value + original index)
    for (int k = 2; k <= 512; k <<= 1) {
        for (int j = k >> 1; j > 0; j >>= 1) {
            for (int rr = 0; rr < 2; ++rr) {
                int i = t + rr * 256;
                int l = i ^ j;
                if (l > i) {
                    float a = s_val[i], c = s_val[l];
                    bool up = ((i & k) == 0);
                    if (up ? (a > c) : (a < c)) {
                        s_val[i] = c; s_val[l] = a;
                        int ia = s_idx[i]; s_idx[i] = s_idx[l]; s_idx[l] = ia;
                    }
                }
            }
            __syncthreads();
        }
    }

    const float M = s_val[511];
    for (int rr = 0; rr < 2; ++rr) {
        int r = t + rr * 256;
        float sv = s_val[r] - M;
        E1[r] = __expf(sv);
        E2[r] = __expf(0.2f * sv);
    }
    __syncthreads();

    // Scalar scans: z1suf[r] = sum_{r'>=r} E1 (z1suf[512]=0);
    //               z2pre[r] = sum_{r'<r} E2 (z2pre[512]=total)
    if (t < 64) {
        float p1 = 0.f, p2 = 0.f;
#pragma unroll
        for (int q = 0; q < 8; ++q) { p1 += E1[t * 8 + q]; p2 += E2[t * 8 + q]; }
        segs1[t] = p1; segs2[t] = p2;
    }
    __syncthreads();
    if (t < 64) {
        float suf = 0.f, pre = 0.f;
        for (int s = t + 1; s < 64; ++s) suf += segs1[s];
        for (int s = 0; s < t; ++s) pre += segs2[s];
        float run = suf;
        for (int q = 7; q >= 0; --q) { run += E1[t * 8 + q]; z1suf[t * 8 + q] = run; }
        float run2 = pre;
        for (int q = 0; q < 8; ++q) { z2pre[t * 8 + q] = run2; run2 += E2[t * 8 + q]; }
        if (t == 63) z2pre[512] = run2;
        if (t == 0) z1suf[512] = 0.f;
    }
    __syncthreads();

    // Per-i: crossover k_i, branch scales, normalizer
    for (int rr = 0; rr < 2; ++rr) {
        int i = t + rr * 256;
        float d = dArr[i];
        int lo = 0, hi = 512;
        while (lo < hi) {
            int mid = (lo + hi) >> 1;
            if (d + s_val[mid] >= 0.f) hi = mid; else lo = mid + 1;
        }
        int k = lo;
        float g = d + M;
        float G = (g >= 0.f) ? g : 0.2f * g;   // keeps denominator >= 1
        float al = __expf(g - G);
        float be = __expf(0.2f * g - G);
        float Z = al * z1suf[k] + be * z2pre[k];
        float inv = 1.0f / Z;
        aZv[i] = al * inv; bZv[i] = be * inv; kArr[i] = k;
    }
    __syncthreads();

    // Channel chunks of 8: weighted suffix (E1*h) + exclusive prefix (E2*h)
    for (int cc = 0; cc < 8; ++cc) {
        for (int rr = 0; rr < 2; ++rr) {
            int r = t + rr * 256;
            int jsrc = s_idx[r];
            const float* hp = h + ((size_t)(b * 512 + jsrc) * 4 + head) * 64 + cc * 8;
            float4 h0 = *(const float4*)(hp);
            float4 h1 = *(const float4*)(hp + 4);
            float e1 = E1[r], e2 = E2[r];
            float hv[8] = {h0.x, h0.y, h0.z, h0.w, h1.x, h1.y, h1.z, h1.w};
#pragma unroll
            for (int c = 0; c < 8; ++c) {
                A1[r * 9 + c] = e1 * hv[c];
                A2[r * 9 + c] = e2 * hv[c];
            }
        }
        __syncthreads();
        {
            int cl = t & 7, seg = t >> 3;
            int r0 = seg * 16;
            float s1 = 0.f, s2 = 0.f;
#pragma unroll
            for (int q = 0; q < 16; ++q) { s1 += A1[(r0 + q) * 9 + cl]; s2 += A2[(r0 + q) * 9 + cl]; }
            segs1[seg * 8 + cl] = s1; segs2[seg * 8 + cl] = s2;
            __syncthreads();
            float suf = 0.f, pre = 0.f;
            for (int s = seg + 1; s < 32; ++s) suf += segs1[s * 8 + cl];
            for (int s = 0; s < seg; ++s) pre += segs2[s * 8 + cl];
            float run = suf;
            for (int q = 15; q >= 0; --q) {
                int r = r0 + q;
                float v = A1[r * 9 + cl];
                run += v;
                A1[r * 9 + cl] = run;            // inclusive suffix
            }
            float run2 = pre;
#pragma unroll
            for (int q = 0; q < 16; ++q) {
                int r = r0 + q;
                float v = A2[r * 9 + cl];
                A2[r * 9 + cl] = run2;           // exclusive prefix
                run2 += v;
            }
            if (seg == 31) tot2[cl] = run2;
        }
        __syncthreads();
        {
            int cl = t & 7;
            int ibase = t >> 3;
#pragma unroll
            for (int p = 0; p < 16; ++p) {
                int i = p * 32 + ibase;
                int k = kArr[i];
                float S1 = (k < 512) ? A1[k * 9 + cl] : 0.f;
                float P2 = (k < 512) ? A2[k * 9 + cl] : tot2[cl];
                float val = aZv[i] * S1 + bZv[i] * P2;
                yH[((size_t)(b * 512 + i) * 4 + head) * 64 + cc * 8 + cl] = val;
            }
        }
        __syncthreads();
    }
}

// ---------------------------------------------------------------------------
// Kernel C: x[bn][c] = relu( mean_h yH[bn][h][c] + bias[c] )
// ---------------------------------------------------------------------------
__global__ __launch_bounds__(256) void finalize_kernel(const float* __restrict__ yH,
                                                       const float* __restrict__ bias,
                                                       float* __restrict__ x) {
    int idx = blockIdx.x * 256 + threadIdx.x;   // over B*N*16 float4 groups
    int bn = idx >> 4, c4 = idx & 15;
    const float* yp = yH + (size_t)bn * 256 + c4 * 4;
    float4 v0 = *(const float4*)(yp);
    float4 v1 = *(const float4*)(yp + 64);
    float4 v2 = *(const float4*)(yp + 128);
    float4 v3 = *(const float4*)(yp + 192);
    float4 bs = *(const float4*)(bias + c4 * 4);
    float4 o;
    o.x = fmaxf(0.25f * (v0.x + v1.x + v2.x + v3.x) + bs.x, 0.f);
    o.y = fmaxf(0.25f * (v0.y + v1.y + v2.y + v3.y) + bs.y, 0.f);
    o.z = fmaxf(0.25f * (v0.z + v1.z + v2.z + v3.z) + bs.z, 0.f);
    o.w = fmaxf(0.25f * (v0.w + v1.w + v2.w + v3.w) + bs.w, 0.f);
    *(float4*)(x + (size_t)bn * 64 + c4 * 4) = o;
}

// ---------------------------------------------------------------------------
// Kernel D: out[b][d] = (mean_n x[b][n][:]) . readout_w[d][:] + readout_b[d]
// ---------------------------------------------------------------------------
__global__ __launch_bounds__(256) void readout_kernel(const float* __restrict__ x,
                                                      const float* __restrict__ rw,
                                                      const float* __restrict__ rb,
                                                      float* __restrict__ out) {
    __shared__ float red[4][64];
    __shared__ float pooled[64];
    int b = blockIdx.x, t = threadIdx.x;
    int c = t & 63, q = t >> 6;
    float acc = 0.f;
    for (int n = q; n < 512; n += 4) acc += x[((size_t)b * 512 + n) * 64 + c];
    red[q][c] = acc;
    __syncthreads();
    if (t < 64) pooled[t] = (red[0][t] + red[1][t] + red[2][t] + red[3][t]) * (1.0f / 512.0f);
    __syncthreads();
    if (t < 64) {
        float a = rb[t];
        for (int cc = 0; cc < 64; ++cc) a += pooled[cc] * rw[t * 64 + cc];
        out[b * 64 + t] = a;
    }
}

extern "C" void kernel_launch(void* const* d_in, const int* in_sizes, int n_in,
                              void* d_out, int out_size, void* d_ws, size_t ws_size,
                              hipStream_t stream) {
    const float* emb       = (const float*)d_in[0];
    const float* lin_w     = (const float*)d_in[1];
    const float* att_src   = (const float*)d_in[2];
    const float* att_dst   = (const float*)d_in[3];
    const float* conv_b    = (const float*)d_in[4];
    const float* readout_w = (const float*)d_in[5];
    const float* readout_b = (const float*)d_in[6];
    float* out = (float*)d_out;

    float* ws   = (float*)d_ws;
    float* xbuf = ws;                 // 2,097,152 floats
    float* hbuf = ws + 2097152;       // 8,388,608 floats (yH aliases hbuf; safe:
                                      // per-(b,head) slices, column-phased writes)

    for (int l = 0; l < 3; ++l) {
        const float* xin = (l == 0) ? emb : xbuf;
        lin_kernel<<<512, 256, 0, stream>>>(xin, lin_w + (size_t)l * 16384, hbuf);
        attn_kernel<<<256, 256, 0, stream>>>(hbuf, att_src + l * 256, att_dst + l * 256, hbuf);
        finalize_kernel<<<2048, 256, 0, stream>>>(hbuf, conv_b + l * 64, xbuf);
    }
    readout_kernel<<<64, 256, 0, stream>>>(xbuf, readout_w, readout_b, out);
}